// Round 4
// baseline (1990.292 us; speedup 1.0000x reference)
//
#include <hip/hip_runtime.h>
#include <stdint.h>

#define NN 384
#define NE 3456
#define NLb 32
#define F 64
#define KD 32

typedef short shortx8 __attribute__((ext_vector_type(8)));
typedef float floatx4 __attribute__((ext_vector_type(4)));

__device__ __forceinline__ float sigm(float v) { return 1.0f / (1.0f + __expf(-v)); }
__device__ __forceinline__ float tanhf_(float v) {
    float x = fminf(fmaxf(v, -15.0f), 15.0f);
    float e = __expf(2.0f * x);
    return (e - 1.0f) / (e + 1.0f);
}
__device__ __forceinline__ uint16_t f2bf(float f) {
    uint32_t u = __float_as_uint(f);
    uint32_t r = (u + 0x7fffu + ((u >> 16) & 1u)) >> 16;
    return (uint16_t)r;
}
__device__ __forceinline__ float bf2f(uint16_t h) {
    return __uint_as_float((uint32_t)h << 16);
}

__global__ void k_zero(float* p, int n) {
    int i = blockIdx.x * 256 + threadIdx.x;
    int st = gridDim.x * 256;
    for (; i < n; i += st) p[i] = 0.0f;
}

__global__ void k_build(const int* __restrict__ e1, const int* __restrict__ e2,
                        float* __restrict__ C, float* __restrict__ Adj) {
    int t = blockIdx.x * 256 + threadIdx.x;
    if (t >= 2 * NE) return;
    int g = t / NE, e = t % NE;
    const int* ei = g ? e2 : e1;
    int s = ei[e], d = ei[NE + e];
    atomicAdd(&C[(size_t)g * NN * NN + d * NN + s], 1.0f);
    if (e < NE - NN) Adj[(size_t)g * NN * NN + s * NN + d] = 1.0f;
}

__global__ void k_degx(const float* __restrict__ f1, const float* __restrict__ f2,
                       const float* __restrict__ Adj, float* __restrict__ X) {
    int g = blockIdx.y;
    int s = blockIdx.x * 64 + threadIdx.x;
    const float* feats = g ? f2 : f1;
    const float* A = Adj + (size_t)g * NN * NN;
    float* Xg = X + (size_t)g * NN * 33;
    float deg = 0.0f;
    for (int d = 0; d < NN; d++) deg += A[s * NN + d];
    for (int c = 0; c < NLb; c++) Xg[s * 33 + c] = feats[s * NLb + c];
    Xg[s * 33 + 32] = deg;
}

__global__ __launch_bounds__(64)
void k_lin0(const float* __restrict__ X, const float* __restrict__ w1,
            const float* __restrict__ b1, const float* __restrict__ w2,
            const float* __restrict__ b2, float* __restrict__ HS) {
    __shared__ float tl[64];
    int g = blockIdx.y, m = blockIdx.x, n = threadIdx.x;
    const float* Xr = X + (size_t)g * NN * 33 + m * 33;
    float t = b1[n];
#pragma unroll
    for (int k = 0; k < 33; k++) t += Xr[k] * w1[k * F + n];
    t = fmaxf(t, 0.0f);
    tl[n] = t;
    __syncthreads();
    float o = b2[n];
#pragma unroll 4
    for (int k = 0; k < F; k++) o += tl[k] * w2[k * F + n];
    HS[(size_t)g * (6 * NN * F) + m * F + n] = o;
}

__global__ __launch_bounds__(64)
void k_gin(const float* __restrict__ C, const float* __restrict__ hin, int hGs,
           const float* __restrict__ gw1, const float* __restrict__ gb1,
           const float* __restrict__ gw2, const float* __restrict__ gb2,
           const float* __restrict__ geps, int li,
           float* __restrict__ zout, int oGs) {
    __shared__ float zl[64], tl[64];
    int g = blockIdx.y, m = blockIdx.x, n = threadIdx.x;
    const float* Crow = C + (size_t)g * NN * NN + (size_t)m * NN;
    const float* h = hin + (size_t)g * hGs;
    float acc = 0.0f;
#pragma unroll 4
    for (int k = 0; k < NN; k++) acc += Crow[k] * h[k * F + n];
    acc += (1.0f + geps[li]) * h[m * F + n];
    zl[n] = acc;
    __syncthreads();
    const float* W1 = gw1 + (size_t)li * F * F;
    const float* W2 = gw2 + (size_t)li * F * F;
    float t = gb1[li * F + n];
#pragma unroll 4
    for (int k = 0; k < F; k++) t += zl[k] * W1[k * F + n];
    t = fmaxf(t, 0.0f);
    tl[n] = t;
    __syncthreads();
    float o = gb2[li * F + n];
#pragma unroll 4
    for (int k = 0; k < F; k++) o += tl[k] * W2[k * F + n];
    zout[(size_t)g * oGs + m * F + n] = o;
}

__global__ __launch_bounds__(256)
void k_bn(float* __restrict__ hsb, int hsGs, float* __restrict__ hbuf, int hGs,
          const float* __restrict__ gamma, const float* __restrict__ beta) {
    __shared__ float red[4][64];
    int g = blockIdx.x;
    float* z = hsb + (size_t)g * hsGs;
    float* h = hbuf + (size_t)g * hGs;
    int c = threadIdx.x & 63, rq = threadIdx.x >> 6;
    int r0 = rq * 96;
    float s = 0.0f;
    for (int r = r0; r < r0 + 96; r++) s += z[r * F + c];
    red[rq][c] = s;
    __syncthreads();
    float mu = (red[0][c] + red[1][c] + red[2][c] + red[3][c]) * (1.0f / NN);
    __syncthreads();
    float v = 0.0f;
    for (int r = r0; r < r0 + 96; r++) { float d = z[r * F + c] - mu; v += d * d; }
    red[rq][c] = v;
    __syncthreads();
    float var = (red[0][c] + red[1][c] + red[2][c] + red[3][c]) * (1.0f / NN);
    float is = rsqrtf(var + 1e-5f);
    float ga = gamma[c], be = beta[c];
    for (int r = r0; r < r0 + 96; r++) {
        float zn = (z[r * F + c] - mu) * is * ga + be;
        z[r * F + c] = zn;
        h[r * F + c] = fmaxf(zn, 0.0f);
    }
}

__global__ void k_cvt2(const float* __restrict__ HS, uint16_t* __restrict__ hhi,
                       uint16_t* __restrict__ hlo) {
    int idx = blockIdx.x * 256 + threadIdx.x;
    if (idx >= 2 * 6 * NN * F) return;
    float v = HS[idx];
    uint16_t h = f2bf(v);
    hhi[idx] = h;
    hlo[idx] = f2bf(v - bf2f(h));
}

__global__ __launch_bounds__(64)
void k_gedT2(const float* __restrict__ ged, uint16_t* __restrict__ ghi,
             uint16_t* __restrict__ glo) {
    __shared__ float t[64 * 65];
    int lk = blockIdx.x, lane = threadIdx.x;
    const float* src = ged + (size_t)lk * 4096;
    for (int d = 0; d < 64; d++) t[lane * 65 + d] = src[d * 64 + lane];
    __syncthreads();
    for (int e = 0; e < 64; e++) {
        float v = t[e * 65 + lane];
        uint16_t h = f2bf(v);
        ghi[(size_t)lk * 4096 + e * 64 + lane] = h;
        glo[(size_t)lk * 4096 + e * 64 + lane] = f2bf(v - bf2f(h));
    }
}

// GRU/attn weight prep: wih/whh row-major [96][32] -> bf16 hi/lo;
// waw, vw [32][32] -> transposed [c][k] bf16 hi/lo.
__global__ __launch_bounds__(256)
void k_wprep(const float* __restrict__ wih, const float* __restrict__ whh,
             const float* __restrict__ waw, const float* __restrict__ vw,
             uint16_t* __restrict__ wihH, uint16_t* __restrict__ wihL,
             uint16_t* __restrict__ whhH, uint16_t* __restrict__ whhL,
             uint16_t* __restrict__ wawTH, uint16_t* __restrict__ wawTL,
             uint16_t* __restrict__ vwTH, uint16_t* __restrict__ vwTL) {
    int t = threadIdx.x;
    for (int idx = t; idx < 3072; idx += 256) {
        float v = wih[idx]; uint16_t h = f2bf(v);
        wihH[idx] = h; wihL[idx] = f2bf(v - bf2f(h));
        v = whh[idx]; h = f2bf(v);
        whhH[idx] = h; whhL[idx] = f2bf(v - bf2f(h));
    }
    for (int idx = t; idx < 1024; idx += 256) {
        int c = idx >> 5, k = idx & 31;
        float v = waw[k * 32 + c]; uint16_t h = f2bf(v);
        wawTH[idx] = h; wawTL[idx] = f2bf(v - bf2f(h));
        v = vw[k * 32 + c]; h = f2bf(v);
        vwTH[idx] = h; vwTL[idx] = f2bf(v - bf2f(h));
    }
}

__global__ __launch_bounds__(256)
void k_t1m2(const uint16_t* __restrict__ gThi, const uint16_t* __restrict__ gTlo,
            const uint16_t* __restrict__ hbhi, const uint16_t* __restrict__ hblo,
            uint16_t* __restrict__ T1hi, uint16_t* __restrict__ T1lo) {
    int l = blockIdx.z;
    int w = threadIdx.x >> 6, lane = threadIdx.x & 63;
    int nb = blockIdx.x * 128 + (w >> 1) * 64;
    int ib = blockIdx.y * 128 + (w & 1) * 64;
    int lr = lane & 15, lq = lane >> 4;
    const uint16_t* gah = gThi + (size_t)l * 2048 * 64;
    const uint16_t* gal = gTlo + (size_t)l * 2048 * 64;
    const uint16_t* gbh = hbhi + (size_t)l * NN * F;
    const uint16_t* gbl = hblo + (size_t)l * NN * F;
    shortx8 Ah[4][2], Al[4][2];
#pragma unroll
    for (int s = 0; s < 4; s++)
#pragma unroll
        for (int ks = 0; ks < 2; ks++) {
            size_t off = (size_t)(nb + s * 16 + lr) * 64 + ks * 32 + lq * 8;
            Ah[s][ks] = *reinterpret_cast<const shortx8*>(gah + off);
            Al[s][ks] = *reinterpret_cast<const shortx8*>(gal + off);
        }
#pragma unroll
    for (int si = 0; si < 4; si++) {
        shortx8 Bh[2], Bl[2];
#pragma unroll
        for (int ks = 0; ks < 2; ks++) {
            size_t off = (size_t)(ib + si * 16 + lr) * 64 + ks * 32 + lq * 8;
            Bh[ks] = *reinterpret_cast<const shortx8*>(gbh + off);
            Bl[ks] = *reinterpret_cast<const shortx8*>(gbl + off);
        }
#pragma unroll
        for (int sn = 0; sn < 4; sn++) {
            floatx4 a = (floatx4){0.f, 0.f, 0.f, 0.f};
#pragma unroll
            for (int ks = 0; ks < 2; ks++) {
                a = __builtin_amdgcn_mfma_f32_16x16x32_bf16(Ah[sn][ks], Bh[ks], a, 0, 0, 0);
                a = __builtin_amdgcn_mfma_f32_16x16x32_bf16(Ah[sn][ks], Bl[ks], a, 0, 0, 0);
                a = __builtin_amdgcn_mfma_f32_16x16x32_bf16(Al[sn][ks], Bh[ks], a, 0, 0, 0);
            }
            size_t addr = ((size_t)l * NN + (ib + si * 16 + lr)) * 2048 + (nb + sn * 16 + lq * 4);
            uint2 hv, lv;
            uint16_t h0 = f2bf(a[0]), h1 = f2bf(a[1]), h2 = f2bf(a[2]), h3 = f2bf(a[3]);
            hv.x = (uint32_t)h0 | ((uint32_t)h1 << 16);
            hv.y = (uint32_t)h2 | ((uint32_t)h3 << 16);
            uint16_t l0 = f2bf(a[0] - bf2f(h0)), l1 = f2bf(a[1] - bf2f(h1));
            uint16_t l2 = f2bf(a[2] - bf2f(h2)), l3 = f2bf(a[3] - bf2f(h3));
            lv.x = (uint32_t)l0 | ((uint32_t)l1 << 16);
            lv.y = (uint32_t)l2 | ((uint32_t)l3 << 16);
            *reinterpret_cast<uint2*>(T1hi + addr) = hv;
            *reinterpret_cast<uint2*>(T1lo + addr) = lv;
        }
    }
}

// x-tile [k=2kt x j=4jt] for layer LL -> xb[j][k] f32 (stride 33)
#define X_MFMA_TO_LDS(LL) do {                                                 \
    const uint16_t* t1h = T1hi + ((size_t)(LL) * NN + i) * 2048;               \
    const uint16_t* t1l = T1lo + ((size_t)(LL) * NN + i) * 2048;               \
    const uint16_t* h2h = hbhi + ((size_t)(6 + (LL)) * NN) * F;                \
    const uint16_t* h2l = hblo + ((size_t)(6 + (LL)) * NN) * F;                \
    shortx8 Ah[2][2], Al[2][2];                                                \
    _Pragma("unroll") for (int kt = 0; kt < 2; kt++)                           \
    _Pragma("unroll") for (int eh = 0; eh < 2; eh++) {                         \
        int off = (kt * 16 + lr) * 64 + eh * 32 + lq * 8;                      \
        Ah[kt][eh] = *reinterpret_cast<const shortx8*>(t1h + off);             \
        Al[kt][eh] = *reinterpret_cast<const shortx8*>(t1l + off);             \
    }                                                                          \
    _Pragma("unroll") for (int jt = 0; jt < 4; jt++) {                         \
        shortx8 Bh[2], Bl[2];                                                  \
        _Pragma("unroll") for (int eh = 0; eh < 2; eh++) {                     \
            int boff = (j0 + jt * 16 + lr) * 64 + eh * 32 + lq * 8;            \
            Bh[eh] = *reinterpret_cast<const shortx8*>(h2h + boff);            \
            Bl[eh] = *reinterpret_cast<const shortx8*>(h2l + boff);            \
        }                                                                      \
        _Pragma("unroll") for (int kt = 0; kt < 2; kt++) {                     \
            floatx4 a = (floatx4){0.f, 0.f, 0.f, 0.f};                         \
            _Pragma("unroll") for (int eh = 0; eh < 2; eh++) {                 \
                a = __builtin_amdgcn_mfma_f32_16x16x32_bf16(Ah[kt][eh], Bh[eh], a, 0, 0, 0); \
                a = __builtin_amdgcn_mfma_f32_16x16x32_bf16(Ah[kt][eh], Bl[eh], a, 0, 0, 0); \
                a = __builtin_amdgcn_mfma_f32_16x16x32_bf16(Al[kt][eh], Bh[eh], a, 0, 0, 0); \
            }                                                                  \
            float* xw = xb + (jt * 16 + lr) * 33 + kt * 16 + lq * 4;           \
            xw[0] = a[0]; xw[1] = a[1]; xw[2] = a[2]; xw[3] = a[3];            \
        }                                                                      \
    }                                                                          \
} while (0)

// build hi/lo bf16 A-frag (row mt*16+lr, k = lq*8+t) from f32 LDS (stride 33)
#define BUILD_AF(H8, L8, SRC, MT) do {                                         \
    _Pragma("unroll") for (int t = 0; t < 8; t++) {                            \
        float fv = (SRC)[((MT) * 16 + lr) * 33 + lq * 8 + t];                  \
        uint16_t hc = f2bf(fv);                                                \
        H8[t] = (short)hc;                                                     \
        L8[t] = (short)f2bf(fv - bf2f(hc));                                    \
    }                                                                          \
} while (0)

#define WFRAG(PTR, GT) (*reinterpret_cast<const shortx8*>((PTR) + ((GT) * 16 + lr) * 32 + lq * 8))

// 1 wave = 64 pairs (i = blockIdx.y, j = blockIdx.x*64 + lane).
// GRU state h and pattern-accumulator live in MFMA C-frag registers:
// [mt][gt0][reg]: row j = mt*16+4*lq+reg, col g = gt0*16+lr.
__global__ __launch_bounds__(64)
void k_mega4(const uint16_t* __restrict__ T1hi, const uint16_t* __restrict__ T1lo,
             const uint16_t* __restrict__ hbhi, const uint16_t* __restrict__ hblo,
             const uint16_t* __restrict__ wihH, const uint16_t* __restrict__ wihL,
             const uint16_t* __restrict__ whhH, const uint16_t* __restrict__ whhL,
             const uint16_t* __restrict__ wawTH, const uint16_t* __restrict__ wawTL,
             const uint16_t* __restrict__ vwTH, const uint16_t* __restrict__ vwTL,
             const float* __restrict__ bih, const float* __restrict__ bhh,
             const float* __restrict__ wab, const float* __restrict__ vat,
             const float* __restrict__ q1w, const float* __restrict__ q1b,
             const float* __restrict__ q2w, const float* __restrict__ q2b,
             const float* __restrict__ kw, const float* __restrict__ kb,
             const float* __restrict__ vb, float* __restrict__ out) {
    __shared__ float xb[64 * 33];
    __shared__ float hb[64 * 33];
    const int i = blockIdx.y;
    const int j0 = blockIdx.x * 64;
    const int lane = threadIdx.x;
    const int lr = lane & 15, lq = lane >> 4;

    // per-lane constants (c/g = lr within 16-col tile)
    const float biasR[2]  = {bih[lr] + bhh[lr], bih[16 + lr] + bhh[16 + lr]};
    const float biasZ[2]  = {bih[32 + lr] + bhh[32 + lr], bih[48 + lr] + bhh[48 + lr]};
    const float biasIN[2] = {bih[64 + lr], bih[80 + lr]};
    const float biasHN[2] = {bhh[64 + lr], bhh[80 + lr]};
    const float wabr[2] = {wab[lr], wab[16 + lr]};
    const float vatr[2] = {vat[lr], vat[16 + lr]};

    float hf[4][2][4], pf[4][2][4];
    float smr[4][4], sdr[4][4];
#pragma unroll
    for (int mt = 0; mt < 4; mt++) {
#pragma unroll
        for (int r = 0; r < 4; r++) { smr[mt][r] = -1e30f; sdr[mt][r] = 0.0f; }
#pragma unroll
        for (int g2 = 0; g2 < 2; g2++)
#pragma unroll
            for (int r = 0; r < 4; r++) { hf[mt][g2][r] = 0.0f; pf[mt][g2][r] = 0.0f; }
    }
    // zero hb (h=0 for layer 0 gh-MFMA)
#pragma unroll
    for (int c = 0; c < 33; c++) hb[lane * 33 + c] = 0.0f;
    __syncthreads();

    // ================= phase A: GRU + layer attention =================
#pragma unroll 1
    for (int l = 0; l < 6; l++) {
        X_MFMA_TO_LDS(l);
        __syncthreads();
#pragma unroll
        for (int mt = 0; mt < 4; mt++) {
            shortx8 xAh, xAl, hAh, hAl;
            BUILD_AF(xAh, xAl, xb, mt);
            BUILD_AF(hAh, hAl, hb, mt);
            floatx4 accRZ[4], accIN[2], accHN[2];
#pragma unroll
            for (int gt = 0; gt < 4; gt++) {
                floatx4 a = (floatx4){0.f, 0.f, 0.f, 0.f};
                shortx8 BiH = WFRAG(wihH, gt), BiL = WFRAG(wihL, gt);
                shortx8 BhH = WFRAG(whhH, gt), BhL = WFRAG(whhL, gt);
                a = __builtin_amdgcn_mfma_f32_16x16x32_bf16(xAh, BiH, a, 0, 0, 0);
                a = __builtin_amdgcn_mfma_f32_16x16x32_bf16(xAh, BiL, a, 0, 0, 0);
                a = __builtin_amdgcn_mfma_f32_16x16x32_bf16(xAl, BiH, a, 0, 0, 0);
                a = __builtin_amdgcn_mfma_f32_16x16x32_bf16(hAh, BhH, a, 0, 0, 0);
                a = __builtin_amdgcn_mfma_f32_16x16x32_bf16(hAh, BhL, a, 0, 0, 0);
                a = __builtin_amdgcn_mfma_f32_16x16x32_bf16(hAl, BhH, a, 0, 0, 0);
                accRZ[gt] = a;
            }
#pragma unroll
            for (int g2 = 0; g2 < 2; g2++) {
                floatx4 a = (floatx4){0.f, 0.f, 0.f, 0.f};
                shortx8 BiH = WFRAG(wihH, 4 + g2), BiL = WFRAG(wihL, 4 + g2);
                a = __builtin_amdgcn_mfma_f32_16x16x32_bf16(xAh, BiH, a, 0, 0, 0);
                a = __builtin_amdgcn_mfma_f32_16x16x32_bf16(xAh, BiL, a, 0, 0, 0);
                a = __builtin_amdgcn_mfma_f32_16x16x32_bf16(xAl, BiH, a, 0, 0, 0);
                accIN[g2] = a;
                floatx4 b = (floatx4){0.f, 0.f, 0.f, 0.f};
                shortx8 BhH = WFRAG(whhH, 4 + g2), BhL = WFRAG(whhL, 4 + g2);
                b = __builtin_amdgcn_mfma_f32_16x16x32_bf16(hAh, BhH, b, 0, 0, 0);
                b = __builtin_amdgcn_mfma_f32_16x16x32_bf16(hAh, BhL, b, 0, 0, 0);
                b = __builtin_amdgcn_mfma_f32_16x16x32_bf16(hAl, BhH, b, 0, 0, 0);
                accHN[g2] = b;
            }
#pragma unroll
            for (int g2 = 0; g2 < 2; g2++)
#pragma unroll
                for (int r = 0; r < 4; r++) {
                    float rg = sigm(accRZ[g2][r] + biasR[g2]);
                    float zg = sigm(accRZ[2 + g2][r] + biasZ[g2]);
                    float ng = tanhf_(accIN[g2][r] + biasIN[g2] + rg * (accHN[g2][r] + biasHN[g2]));
                    hf[mt][g2][r] = (1.0f - zg) * ng + zg * hf[mt][g2][r];
                }
        }
        // write h C-frag -> hb
#pragma unroll
        for (int mt = 0; mt < 4; mt++)
#pragma unroll
            for (int g2 = 0; g2 < 2; g2++)
#pragma unroll
                for (int r = 0; r < 4; r++)
                    hb[(mt * 16 + 4 * lq + r) * 33 + g2 * 16 + lr] = hf[mt][g2][r];
        __syncthreads();
        // attention: t = h @ wawT, sc = sum_c tanh(t+wab)*vat, online softmax
#pragma unroll
        for (int mt = 0; mt < 4; mt++) {
            shortx8 hAh, hAl;
            BUILD_AF(hAh, hAl, hb, mt);
            floatx4 tacc[2];
#pragma unroll
            for (int ct = 0; ct < 2; ct++) {
                floatx4 a = (floatx4){0.f, 0.f, 0.f, 0.f};
                shortx8 BH = WFRAG(wawTH, ct), BL = WFRAG(wawTL, ct);
                a = __builtin_amdgcn_mfma_f32_16x16x32_bf16(hAh, BH, a, 0, 0, 0);
                a = __builtin_amdgcn_mfma_f32_16x16x32_bf16(hAh, BL, a, 0, 0, 0);
                a = __builtin_amdgcn_mfma_f32_16x16x32_bf16(hAl, BH, a, 0, 0, 0);
                tacc[ct] = a;
            }
            float rs[4];
#pragma unroll
            for (int r = 0; r < 4; r++)
                rs[r] = tanhf_(tacc[0][r] + wabr[0]) * vatr[0]
                      + tanhf_(tacc[1][r] + wabr[1]) * vatr[1];
#pragma unroll
            for (int m = 1; m < 16; m <<= 1)
#pragma unroll
                for (int r = 0; r < 4; r++) rs[r] += __shfl_xor(rs[r], m, 64);
#pragma unroll
            for (int r = 0; r < 4; r++) {
                float nm = fmaxf(smr[mt][r], rs[r]);
                float eo = __expf(smr[mt][r] - nm), en = __expf(rs[r] - nm);
                sdr[mt][r] = sdr[mt][r] * eo + en;
                smr[mt][r] = nm;
#pragma unroll
                for (int g2 = 0; g2 < 2; g2++)
                    pf[mt][g2][r] = pf[mt][g2][r] * eo + en * hf[mt][g2][r];
            }
        }
        __syncthreads();
    }

    // normalize pattern, hand off to per-thread layout via xb
#pragma unroll
    for (int mt = 0; mt < 4; mt++)
#pragma unroll
        for (int r = 0; r < 4; r++) {
            float inv = 1.0f / sdr[mt][r];
#pragma unroll
            for (int g2 = 0; g2 < 2; g2++)
                xb[(mt * 16 + 4 * lq + r) * 33 + g2 * 16 + lr] = pf[mt][g2][r] * inv;
        }
    __syncthreads();

    // ---------------- per-thread: pattern -> q -> qk ----------------
    float patt[KD];
#pragma unroll
    for (int k = 0; k < KD; k++) patt[k] = xb[lane * 33 + k];
    float t1r[KD];
#pragma unroll
    for (int c = 0; c < KD; c++) {
        float t = q1b[c];
#pragma unroll
        for (int k = 0; k < KD; k++) t += patt[k] * q1w[k * KD + c];
        t1r[c] = fmaxf(t, 0.0f);
    }
    float q[KD];
#pragma unroll
    for (int c = 0; c < KD; c++) {
        float t = q2b[c];
#pragma unroll
        for (int k = 0; k < KD; k++) t += t1r[k] * q2w[k * KD + c];
        q[c] = t;
    }
    float qdotb = 0.0f;
#pragma unroll
    for (int c = 0; c < KD; c++) qdotb += q[c] * kb[c];
    float qk[KD];
#pragma unroll
    for (int k = 0; k < KD; k++) {
        float t = 0.0f;
#pragma unroll
        for (int c = 0; c < KD; c++) t += q[c] * kw[k * KD + c];
        qk[k] = t;
    }

    // ================= phase B: scores + context =================
    float ctx[KD];
#pragma unroll
    for (int k = 0; k < KD; k++) ctx[k] = 0.0f;
    float s2m = -1e30f, s2den = 0.0f;
#pragma unroll 1
    for (int l = 0; l < 6; l++) {
        X_MFMA_TO_LDS(l);
        __syncthreads();
        // per-thread score
        float s = qdotb;
#pragma unroll
        for (int k = 0; k < KD; k++) s += xb[lane * 33 + k] * qk[k];
        s *= 0.17677669529663687f;
        float nm = fmaxf(s2m, s);
        float eo = __expf(s2m - nm), en = __expf(s - nm);
        s2den = s2den * eo + en;
        s2m = nm;
        // vv = x @ vwT via MFMA -> hb
#pragma unroll
        for (int mt = 0; mt < 4; mt++) {
            shortx8 xAh, xAl;
            BUILD_AF(xAh, xAl, xb, mt);
#pragma unroll
            for (int ct = 0; ct < 2; ct++) {
                floatx4 a = (floatx4){0.f, 0.f, 0.f, 0.f};
                shortx8 BH = WFRAG(vwTH, ct), BL = WFRAG(vwTL, ct);
                a = __builtin_amdgcn_mfma_f32_16x16x32_bf16(xAh, BH, a, 0, 0, 0);
                a = __builtin_amdgcn_mfma_f32_16x16x32_bf16(xAh, BL, a, 0, 0, 0);
                a = __builtin_amdgcn_mfma_f32_16x16x32_bf16(xAl, BH, a, 0, 0, 0);
#pragma unroll
                for (int r = 0; r < 4; r++)
                    hb[(mt * 16 + 4 * lq + r) * 33 + ct * 16 + lr] = a[r];
            }
        }
        __syncthreads();
#pragma unroll
        for (int c = 0; c < KD; c++)
            ctx[c] = ctx[c] * eo + en * (hb[lane * 33 + c] + vb[c]);
        __syncthreads();
    }
    float invd = 1.0f / s2den;
    float* op = out + ((size_t)i * NN + j0 + lane) * KD;
#pragma unroll
    for (int k = 0; k < KD; k += 4) {
        float4 w4;
        w4.x = ctx[k] * invd; w4.y = ctx[k + 1] * invd;
        w4.z = ctx[k + 2] * invd; w4.w = ctx[k + 3] * invd;
        *reinterpret_cast<float4*>(op + k) = w4;
    }
}

extern "C" void kernel_launch(void* const* d_in, const int* in_sizes, int n_in,
                              void* d_out, int out_size, void* d_ws, size_t ws_size,
                              hipStream_t stream) {
    const float* f1   = (const float*)d_in[0];
    const float* f2   = (const float*)d_in[1];
    const float* l0w1 = (const float*)d_in[2];
    const float* l0b1 = (const float*)d_in[3];
    const float* l0w2 = (const float*)d_in[4];
    const float* l0b2 = (const float*)d_in[5];
    const float* geps = (const float*)d_in[6];
    const float* gw1  = (const float*)d_in[7];
    const float* gb1  = (const float*)d_in[8];
    const float* gw2  = (const float*)d_in[9];
    const float* gb2  = (const float*)d_in[10];
    const float* gga  = (const float*)d_in[11];
    const float* gbe  = (const float*)d_in[12];
    const float* ged  = (const float*)d_in[13];
    const float* wih  = (const float*)d_in[14];
    const float* whh  = (const float*)d_in[15];
    const float* bih  = (const float*)d_in[16];
    const float* bhh  = (const float*)d_in[17];
    const float* waw  = (const float*)d_in[18];
    const float* wab  = (const float*)d_in[19];
    const float* vat  = (const float*)d_in[20];
    const float* q1w  = (const float*)d_in[21];
    const float* q1b  = (const float*)d_in[22];
    const float* q2w  = (const float*)d_in[23];
    const float* q2b  = (const float*)d_in[24];
    const float* kw   = (const float*)d_in[25];
    const float* kb   = (const float*)d_in[26];
    const float* vw   = (const float*)d_in[27];
    const float* vb   = (const float*)d_in[28];
    const int*   e1   = (const int*)d_in[29];
    const int*   e2   = (const int*)d_in[30];

    // ---- workspace layout ----
    float* C   = (float*)d_ws;                                 // 2*NN*NN
    float* Adj = C + (size_t)2 * NN * NN;                      // 2*NN*NN
    float* X   = Adj + (size_t)2 * NN * NN;                    // 2*NN*33
    float* H   = X + (size_t)2 * NN * 33;                      // 2*NN*F
    float* HS  = H + (size_t)2 * NN * F;                       // [2][6][NN][F]
    uint16_t* hbhi = (uint16_t*)(HS + (size_t)2 * 6 * NN * F); // [2][6][NN][F]
    uint16_t* hblo = hbhi + (size_t)2 * 6 * NN * F;
    uint16_t* gThi = hblo + (size_t)2 * 6 * NN * F;            // [6][2048][64]
    uint16_t* gTlo = gThi + (size_t)6 * 2048 * 64;
    uint16_t* T1hi = gTlo + (size_t)6 * 2048 * 64;             // [6][NN][2048]
    uint16_t* T1lo = T1hi + (size_t)6 * NN * 2048;
    uint16_t* wihH = T1lo + (size_t)6 * NN * 2048;             // [96][32]
    uint16_t* wihL = wihH + 3072;
    uint16_t* whhH = wihL + 3072;
    uint16_t* whhL = whhH + 3072;
    uint16_t* wawTH = whhL + 3072;                             // [32][32]
    uint16_t* wawTL = wawTH + 1024;
    uint16_t* vwTH  = wawTL + 1024;
    uint16_t* vwTL  = vwTH + 1024;
    float* out = (float*)d_out;

    const int GHS = 6 * NN * F;
    const int GH  = NN * F;

    k_zero<<<576, 256, 0, stream>>>(C, 4 * NN * NN);
    k_build<<<(2 * NE + 255) / 256, 256, 0, stream>>>(e1, e2, C, Adj);
    k_degx<<<dim3(6, 2), 64, 0, stream>>>(f1, f2, Adj, X);
    k_lin0<<<dim3(NN, 2), 64, 0, stream>>>(X, l0w1, l0b1, l0w2, l0b2, HS);
    for (int li = 0; li < 5; li++) {
        const float* hp = (li == 0) ? HS : H;
        int hGs = (li == 0) ? GHS : GH;
        k_gin<<<dim3(NN, 2), 64, 0, stream>>>(C, hp, hGs, gw1, gb1, gw2, gb2,
                                              geps, li, HS + (li + 1) * GH, GHS);
        k_bn<<<2, 256, 0, stream>>>(HS + (li + 1) * GH, GHS, H, GH,
                                    gga + li * F, gbe + li * F);
    }
    k_cvt2<<<(2 * 6 * NN * F + 255) / 256, 256, 0, stream>>>(HS, hbhi, hblo);
    k_gedT2<<<6 * KD, 64, 0, stream>>>(ged, gThi, gTlo);
    k_wprep<<<1, 256, 0, stream>>>(wih, whh, waw, vw, wihH, wihL, whhH, whhL,
                                   wawTH, wawTL, vwTH, vwTL);
    k_t1m2<<<dim3(16, 3, 6), 256, 0, stream>>>(gThi, gTlo, hbhi, hblo, T1hi, T1lo);
    k_mega4<<<dim3(6, NN), 64, 0, stream>>>(T1hi, T1lo, hbhi, hblo,
                                            wihH, wihL, whhH, whhL,
                                            wawTH, wawTL, vwTH, vwTL,
                                            bih, bhh, wab, vat,
                                            q1w, q1b, q2w, q2b, kw, kb, vb, out);
}

// Round 5
// 1772.877 us; speedup vs baseline: 1.1226x; 1.1226x over previous
//
#include <hip/hip_runtime.h>
#include <stdint.h>

#define NN 384
#define NE 3456
#define NLb 32
#define F 64
#define KD 32

typedef short shortx8 __attribute__((ext_vector_type(8)));
typedef float floatx4 __attribute__((ext_vector_type(4)));

__device__ __forceinline__ float sigm(float v) { return 1.0f / (1.0f + __expf(-v)); }
__device__ __forceinline__ float tanhf_(float v) {
    float x = fminf(fmaxf(v, -15.0f), 15.0f);
    float e = __expf(2.0f * x);
    return (e - 1.0f) / (e + 1.0f);
}
__device__ __forceinline__ uint16_t f2bf(float f) {
    uint32_t u = __float_as_uint(f);
    uint32_t r = (u + 0x7fffu + ((u >> 16) & 1u)) >> 16;
    return (uint16_t)r;
}
__device__ __forceinline__ float bf2f(uint16_t h) {
    return __uint_as_float((uint32_t)h << 16);
}

__global__ void k_zero(float* p, int n) {
    int i = blockIdx.x * 256 + threadIdx.x;
    int st = gridDim.x * 256;
    for (; i < n; i += st) p[i] = 0.0f;
}

__global__ void k_build(const int* __restrict__ e1, const int* __restrict__ e2,
                        float* __restrict__ C, float* __restrict__ Adj) {
    int t = blockIdx.x * 256 + threadIdx.x;
    if (t >= 2 * NE) return;
    int g = t / NE, e = t % NE;
    const int* ei = g ? e2 : e1;
    int s = ei[e], d = ei[NE + e];
    atomicAdd(&C[(size_t)g * NN * NN + d * NN + s], 1.0f);
    if (e < NE - NN) Adj[(size_t)g * NN * NN + s * NN + d] = 1.0f;
}

__global__ void k_degx(const float* __restrict__ f1, const float* __restrict__ f2,
                       const float* __restrict__ Adj, float* __restrict__ X) {
    int g = blockIdx.y;
    int s = blockIdx.x * 64 + threadIdx.x;
    const float* feats = g ? f2 : f1;
    const float* A = Adj + (size_t)g * NN * NN;
    float* Xg = X + (size_t)g * NN * 33;
    float deg = 0.0f;
    for (int d = 0; d < NN; d++) deg += A[s * NN + d];
    for (int c = 0; c < NLb; c++) Xg[s * 33 + c] = feats[s * NLb + c];
    Xg[s * 33 + 32] = deg;
}

__global__ __launch_bounds__(64)
void k_lin0(const float* __restrict__ X, const float* __restrict__ w1,
            const float* __restrict__ b1, const float* __restrict__ w2,
            const float* __restrict__ b2, float* __restrict__ HS) {
    __shared__ float tl[64];
    int g = blockIdx.y, m = blockIdx.x, n = threadIdx.x;
    const float* Xr = X + (size_t)g * NN * 33 + m * 33;
    float t = b1[n];
#pragma unroll
    for (int k = 0; k < 33; k++) t += Xr[k] * w1[k * F + n];
    t = fmaxf(t, 0.0f);
    tl[n] = t;
    __syncthreads();
    float o = b2[n];
#pragma unroll 4
    for (int k = 0; k < F; k++) o += tl[k] * w2[k * F + n];
    HS[(size_t)g * (6 * NN * F) + m * F + n] = o;
}

__global__ __launch_bounds__(64)
void k_gin(const float* __restrict__ C, const float* __restrict__ hin, int hGs,
           const float* __restrict__ gw1, const float* __restrict__ gb1,
           const float* __restrict__ gw2, const float* __restrict__ gb2,
           const float* __restrict__ geps, int li,
           float* __restrict__ zout, int oGs) {
    __shared__ float zl[64], tl[64];
    int g = blockIdx.y, m = blockIdx.x, n = threadIdx.x;
    const float* Crow = C + (size_t)g * NN * NN + (size_t)m * NN;
    const float* h = hin + (size_t)g * hGs;
    float acc = 0.0f;
#pragma unroll 4
    for (int k = 0; k < NN; k++) acc += Crow[k] * h[k * F + n];
    acc += (1.0f + geps[li]) * h[m * F + n];
    zl[n] = acc;
    __syncthreads();
    const float* W1 = gw1 + (size_t)li * F * F;
    const float* W2 = gw2 + (size_t)li * F * F;
    float t = gb1[li * F + n];
#pragma unroll 4
    for (int k = 0; k < F; k++) t += zl[k] * W1[k * F + n];
    t = fmaxf(t, 0.0f);
    tl[n] = t;
    __syncthreads();
    float o = gb2[li * F + n];
#pragma unroll 4
    for (int k = 0; k < F; k++) o += tl[k] * W2[k * F + n];
    zout[(size_t)g * oGs + m * F + n] = o;
}

__global__ __launch_bounds__(256)
void k_bn(float* __restrict__ hsb, int hsGs, float* __restrict__ hbuf, int hGs,
          const float* __restrict__ gamma, const float* __restrict__ beta) {
    __shared__ float red[4][64];
    int g = blockIdx.x;
    float* z = hsb + (size_t)g * hsGs;
    float* h = hbuf + (size_t)g * hGs;
    int c = threadIdx.x & 63, rq = threadIdx.x >> 6;
    int r0 = rq * 96;
    float s = 0.0f;
    for (int r = r0; r < r0 + 96; r++) s += z[r * F + c];
    red[rq][c] = s;
    __syncthreads();
    float mu = (red[0][c] + red[1][c] + red[2][c] + red[3][c]) * (1.0f / NN);
    __syncthreads();
    float v = 0.0f;
    for (int r = r0; r < r0 + 96; r++) { float d = z[r * F + c] - mu; v += d * d; }
    red[rq][c] = v;
    __syncthreads();
    float var = (red[0][c] + red[1][c] + red[2][c] + red[3][c]) * (1.0f / NN);
    float is = rsqrtf(var + 1e-5f);
    float ga = gamma[c], be = beta[c];
    for (int r = r0; r < r0 + 96; r++) {
        float zn = (z[r * F + c] - mu) * is * ga + be;
        z[r * F + c] = zn;
        h[r * F + c] = fmaxf(zn, 0.0f);
    }
}

// f32 HS (graph 1 only) -> bf16 hi/lo
__global__ void k_cvt2(const float* __restrict__ HS, uint16_t* __restrict__ hhi,
                       uint16_t* __restrict__ hlo) {
    int idx = blockIdx.x * 256 + threadIdx.x;
    if (idx >= 6 * NN * F) return;
    float v = HS[idx];
    uint16_t h = f2bf(v);
    hhi[idx] = h;
    hlo[idx] = f2bf(v - bf2f(h));
}

__global__ __launch_bounds__(64)
void k_gedT2(const float* __restrict__ ged, uint16_t* __restrict__ ghi,
             uint16_t* __restrict__ glo) {
    __shared__ float t[64 * 65];
    int lk = blockIdx.x, lane = threadIdx.x;
    const float* src = ged + (size_t)lk * 4096;
    for (int d = 0; d < 64; d++) t[lane * 65 + d] = src[d * 64 + lane];
    __syncthreads();
    for (int e = 0; e < 64; e++) {
        float v = t[e * 65 + lane];
        uint16_t h = f2bf(v);
        ghi[(size_t)lk * 4096 + e * 64 + lane] = h;
        glo[(size_t)lk * 4096 + e * 64 + lane] = f2bf(v - bf2f(h));
    }
}

// wpack (f32): [0 wih 3072][3072 whh 3072][6144 wawT 1024][7168 vwT 1024]
// [8192 bih 96][8288 bhh 96][8384 wab 32][8416 vat 32][8448 vb 32]  total 8480
__global__ __launch_bounds__(256)
void k_wprep3(const float* __restrict__ wih, const float* __restrict__ whh,
              const float* __restrict__ waw, const float* __restrict__ vw,
              const float* __restrict__ bih, const float* __restrict__ bhh,
              const float* __restrict__ wab, const float* __restrict__ vat,
              const float* __restrict__ vb, float* __restrict__ wp) {
    int t = threadIdx.x;
    for (int idx = t; idx < 3072; idx += 256) {
        wp[idx] = wih[idx];
        wp[3072 + idx] = whh[idx];
    }
    for (int idx = t; idx < 1024; idx += 256) {
        int c = idx >> 5, k = idx & 31;
        wp[6144 + idx] = waw[k * 32 + c];
        wp[7168 + idx] = vw[k * 32 + c];
    }
    if (t < 96) { wp[8192 + t] = bih[t]; wp[8288 + t] = bhh[t]; }
    if (t < 32) { wp[8384 + t] = wab[t]; wp[8416 + t] = vat[t]; wp[8448 + t] = vb[t]; }
}

// T1f[l,i,n=k*64+e] = sum_d gedT[l,n,d]*h1[l,i,d]  (hi/lo MFMA, f32 out)
__global__ __launch_bounds__(256)
void k_t1m2(const uint16_t* __restrict__ gThi, const uint16_t* __restrict__ gTlo,
            const uint16_t* __restrict__ hbhi, const uint16_t* __restrict__ hblo,
            float* __restrict__ T1f) {
    int l = blockIdx.z;
    int w = threadIdx.x >> 6, lane = threadIdx.x & 63;
    int nb = blockIdx.x * 128 + (w >> 1) * 64;
    int ib = blockIdx.y * 128 + (w & 1) * 64;
    int lr = lane & 15, lq = lane >> 4;
    const uint16_t* gah = gThi + (size_t)l * 2048 * 64;
    const uint16_t* gal = gTlo + (size_t)l * 2048 * 64;
    const uint16_t* gbh = hbhi + (size_t)l * NN * F;
    const uint16_t* gbl = hblo + (size_t)l * NN * F;
    shortx8 Ah[4][2], Al[4][2];
#pragma unroll
    for (int s = 0; s < 4; s++)
#pragma unroll
        for (int ks = 0; ks < 2; ks++) {
            size_t off = (size_t)(nb + s * 16 + lr) * 64 + ks * 32 + lq * 8;
            Ah[s][ks] = *reinterpret_cast<const shortx8*>(gah + off);
            Al[s][ks] = *reinterpret_cast<const shortx8*>(gal + off);
        }
#pragma unroll
    for (int si = 0; si < 4; si++) {
        shortx8 Bh[2], Bl[2];
#pragma unroll
        for (int ks = 0; ks < 2; ks++) {
            size_t off = (size_t)(ib + si * 16 + lr) * 64 + ks * 32 + lq * 8;
            Bh[ks] = *reinterpret_cast<const shortx8*>(gbh + off);
            Bl[ks] = *reinterpret_cast<const shortx8*>(gbl + off);
        }
#pragma unroll
        for (int sn = 0; sn < 4; sn++) {
            floatx4 a = (floatx4){0.f, 0.f, 0.f, 0.f};
#pragma unroll
            for (int ks = 0; ks < 2; ks++) {
                a = __builtin_amdgcn_mfma_f32_16x16x32_bf16(Ah[sn][ks], Bh[ks], a, 0, 0, 0);
                a = __builtin_amdgcn_mfma_f32_16x16x32_bf16(Ah[sn][ks], Bl[ks], a, 0, 0, 0);
                a = __builtin_amdgcn_mfma_f32_16x16x32_bf16(Al[sn][ks], Bh[ks], a, 0, 0, 0);
            }
            size_t addr = ((size_t)l * NN + (ib + si * 16 + lr)) * 2048 + (nb + sn * 16 + lq * 4);
            *reinterpret_cast<floatx4*>(T1f + addr) = a;
        }
    }
}

// Block = 192 threads, grid (2, NN): i = blockIdx.y, j = blockIdx.x*192 + TX.
// All loop-resident weights in LDS (broadcast reads); T1(l,i) tile (f32, 8KB)
// in LDS per layer; x computed per-thread f32; GRU/attention per-thread f32.
__global__ __launch_bounds__(192)
void k_mega6(const float* __restrict__ T1f, const float* __restrict__ HS2,
             const float* __restrict__ wpack,
             const float* __restrict__ q1w, const float* __restrict__ q1b,
             const float* __restrict__ q2w, const float* __restrict__ q2b,
             const float* __restrict__ kw, const float* __restrict__ kb,
             float* __restrict__ out) {
    __shared__ float wl[8480];
    __shared__ float t1l[2048];
    __shared__ float hl[192 * 33];
    const int i = blockIdx.y;
    const int TX = threadIdx.x;
    const int j = blockIdx.x * 192 + TX;

    for (int idx = TX; idx < 8480; idx += 192) wl[idx] = wpack[idx];
    const float* wihL = wl;
    const float* whhL = wl + 3072;
    const float* wawT = wl + 6144;
    const float* vwT  = wl + 7168;
    const float* bihL = wl + 8192;
    const float* bhhL = wl + 8288;
    const float* wabL = wl + 8384;
    const float* vatL = wl + 8416;
    const float* vbL  = wl + 8448;

    float hreg[KD], patt[KD];
#pragma unroll
    for (int k = 0; k < KD; k++) { hreg[k] = 0.0f; patt[k] = 0.0f; hl[TX * 33 + k] = 0.0f; }
    float sm = -1e30f, sden = 0.0f;

#define FILL_T1(LL) do {                                                       \
    __syncthreads();                                                           \
    const float4* srcp = reinterpret_cast<const float4*>(                      \
        T1f + ((size_t)(LL) * NN + i) * 2048);                                 \
    for (int idx = TX; idx < 512; idx += 192)                                  \
        reinterpret_cast<float4*>(t1l)[idx] = srcp[idx];                       \
    __syncthreads();                                                           \
} while (0)

#define COMPUTE_X6(LL) do {                                                    \
    float4 hv[16];                                                             \
    const float4* h2p = reinterpret_cast<const float4*>(                       \
        HS2 + ((size_t)(LL) * NN + j) * 64);                                   \
    _Pragma("unroll") for (int qq = 0; qq < 16; qq++) hv[qq] = h2p[qq];        \
    _Pragma("unroll") for (int k = 0; k < KD; k++) x[k] = 0.0f;                \
    _Pragma("unroll 2")                                                        \
    for (int eb = 0; eb < 8; eb++) {                                           \
        float h0 = hv[eb * 2].x, h1 = hv[eb * 2].y;                            \
        float h2v = hv[eb * 2].z, h3 = hv[eb * 2].w;                           \
        float h4 = hv[eb * 2 + 1].x, h5 = hv[eb * 2 + 1].y;                    \
        float h6 = hv[eb * 2 + 1].z, h7 = hv[eb * 2 + 1].w;                    \
        _Pragma("unroll") for (int k = 0; k < KD; k++) {                       \
            const float* tp = t1l + k * 64 + eb * 8;                           \
            x[k] += tp[0] * h0 + tp[1] * h1 + tp[2] * h2v + tp[3] * h3         \
                  + tp[4] * h4 + tp[5] * h5 + tp[6] * h6 + tp[7] * h7;         \
        }                                                                      \
    }                                                                          \
} while (0)

    // ================= phase A: GRU + layer attention =================
#pragma unroll 1
    for (int l = 0; l < 6; l++) {
        FILL_T1(l);
        float x[KD];
        COMPUTE_X6(l);
#pragma unroll 2
        for (int g = 0; g < KD; g++) {
            float ir = bihL[g],           hr = bhhL[g];
            float iz = bihL[KD + g],      hz = bhhL[KD + g];
            float in2 = bihL[2 * KD + g], hn2 = bhhL[2 * KD + g];
            const float* wiR = wihL + g * KD;
            const float* wiZ = wihL + (KD + g) * KD;
            const float* wiN = wihL + (2 * KD + g) * KD;
            const float* whR = whhL + g * KD;
            const float* whZ = whhL + (KD + g) * KD;
            const float* whN = whhL + (2 * KD + g) * KD;
#pragma unroll
            for (int k = 0; k < KD; k++) {
                float xk = x[k], hk = hreg[k];
                ir += xk * wiR[k]; iz += xk * wiZ[k]; in2 += xk * wiN[k];
                hr += hk * whR[k]; hz += hk * whZ[k]; hn2 += hk * whN[k];
            }
            float r  = sigm(ir + hr);
            float zg = sigm(iz + hz);
            float ng = tanhf_(in2 + r * hn2);
            float hold = hl[TX * 33 + g];
            hl[TX * 33 + g] = (1.0f - zg) * ng + zg * hold;
        }
#pragma unroll
        for (int k = 0; k < KD; k++) hreg[k] = hl[TX * 33 + k];
        float sc = 0.0f;
#pragma unroll 1
        for (int c = 0; c < KD; c++) {
            float t = wabL[c];
            const float* wr = wawT + c * KD;
#pragma unroll
            for (int k = 0; k < KD; k++) t += hreg[k] * wr[k];
            sc += tanhf_(t) * vatL[c];
        }
        float nm = fmaxf(sm, sc);
        float eo = __expf(sm - nm), en = __expf(sc - nm);
        sden = sden * eo + en;
        sm = nm;
#pragma unroll
        for (int k = 0; k < KD; k++) patt[k] = patt[k] * eo + en * hreg[k];
    }

    // ---------------- per-thread: pattern -> q -> qk (one-time) ----------------
    float inv = 1.0f / sden;
#pragma unroll
    for (int k = 0; k < KD; k++) patt[k] *= inv;
    float t1r[KD];
#pragma unroll
    for (int c = 0; c < KD; c++) {
        float t = q1b[c];
#pragma unroll
        for (int k = 0; k < KD; k++) t += patt[k] * q1w[k * KD + c];
        t1r[c] = fmaxf(t, 0.0f);
    }
    float q[KD];
#pragma unroll
    for (int c = 0; c < KD; c++) {
        float t = q2b[c];
#pragma unroll
        for (int k = 0; k < KD; k++) t += t1r[k] * q2w[k * KD + c];
        q[c] = t;
    }
    float qdotb = 0.0f;
#pragma unroll
    for (int c = 0; c < KD; c++) qdotb += q[c] * kb[c];
    float qk[KD];
#pragma unroll
    for (int k = 0; k < KD; k++) {
        float t = 0.0f;
#pragma unroll
        for (int c = 0; c < KD; c++) t += q[c] * kw[k * KD + c];
        qk[k] = t;
    }

    // ================= phase B: scores + context =================
    float ctx[KD];
#pragma unroll
    for (int k = 0; k < KD; k++) ctx[k] = 0.0f;
    float s2m = -1e30f, s2den = 0.0f;
#pragma unroll 1
    for (int l = 0; l < 6; l++) {
        FILL_T1(l);
        float x[KD];
        COMPUTE_X6(l);
        float s = qdotb;
#pragma unroll
        for (int k = 0; k < KD; k++) s += x[k] * qk[k];
        s *= 0.17677669529663687f;
        float nm = fmaxf(s2m, s);
        float eo = __expf(s2m - nm), en = __expf(s - nm);
        s2den = s2den * eo + en;
        s2m = nm;
#pragma unroll 2
        for (int c = 0; c < KD; c++) {
            float vc = vbL[c];
            const float* vr = vwT + c * KD;
#pragma unroll
            for (int k = 0; k < KD; k++) vc += x[k] * vr[k];
            ctx[c] = ctx[c] * eo + en * vc;
        }
    }
    float invd = 1.0f / s2den;
    float* op = out + ((size_t)i * NN + j) * KD;
#pragma unroll
    for (int k = 0; k < KD; k += 4) {
        float4 w4;
        w4.x = ctx[k] * invd; w4.y = ctx[k + 1] * invd;
        w4.z = ctx[k + 2] * invd; w4.w = ctx[k + 3] * invd;
        *reinterpret_cast<float4*>(op + k) = w4;
    }
#undef FILL_T1
#undef COMPUTE_X6
}

extern "C" void kernel_launch(void* const* d_in, const int* in_sizes, int n_in,
                              void* d_out, int out_size, void* d_ws, size_t ws_size,
                              hipStream_t stream) {
    const float* f1   = (const float*)d_in[0];
    const float* f2   = (const float*)d_in[1];
    const float* l0w1 = (const float*)d_in[2];
    const float* l0b1 = (const float*)d_in[3];
    const float* l0w2 = (const float*)d_in[4];
    const float* l0b2 = (const float*)d_in[5];
    const float* geps = (const float*)d_in[6];
    const float* gw1  = (const float*)d_in[7];
    const float* gb1  = (const float*)d_in[8];
    const float* gw2  = (const float*)d_in[9];
    const float* gb2  = (const float*)d_in[10];
    const float* gga  = (const float*)d_in[11];
    const float* gbe  = (const float*)d_in[12];
    const float* ged  = (const float*)d_in[13];
    const float* wih  = (const float*)d_in[14];
    const float* whh  = (const float*)d_in[15];
    const float* bih  = (const float*)d_in[16];
    const float* bhh  = (const float*)d_in[17];
    const float* waw  = (const float*)d_in[18];
    const float* wab  = (const float*)d_in[19];
    const float* vat  = (const float*)d_in[20];
    const float* q1w  = (const float*)d_in[21];
    const float* q1b  = (const float*)d_in[22];
    const float* q2w  = (const float*)d_in[23];
    const float* q2b  = (const float*)d_in[24];
    const float* kw   = (const float*)d_in[25];
    const float* kb   = (const float*)d_in[26];
    const float* vw   = (const float*)d_in[27];
    const float* vb   = (const float*)d_in[28];
    const int*   e1   = (const int*)d_in[29];
    const int*   e2   = (const int*)d_in[30];

    // ---- workspace layout (floats then u16) ----
    float* C     = (float*)d_ws;                        // 2*NN*NN   = 294912
    float* Adj   = C + (size_t)2 * NN * NN;             // 294912
    float* X     = Adj + (size_t)2 * NN * NN;           // 2*NN*33   = 25344
    float* H     = X + (size_t)2 * NN * 33;             // 2*NN*F    = 49152
    float* HS    = H + (size_t)2 * NN * F;              // 2*6*NN*F  = 294912
    float* T1f   = HS + (size_t)2 * 6 * NN * F;         // 6*NN*2048 = 4718592
    float* wpack = T1f + (size_t)6 * NN * 2048;         // 8480
    uint16_t* hbhi = (uint16_t*)(wpack + 8480);         // 6*NN*F = 147456
    uint16_t* hblo = hbhi + (size_t)6 * NN * F;
    uint16_t* gThi = hblo + (size_t)6 * NN * F;         // 6*2048*64 = 786432
    uint16_t* gTlo = gThi + (size_t)6 * 2048 * 64;
    float* out = (float*)d_out;

    const int GHS = 6 * NN * F;
    const int GH  = NN * F;

    k_zero<<<576, 256, 0, stream>>>(C, 4 * NN * NN);
    k_build<<<(2 * NE + 255) / 256, 256, 0, stream>>>(e1, e2, C, Adj);
    k_degx<<<dim3(6, 2), 64, 0, stream>>>(f1, f2, Adj, X);
    k_lin0<<<dim3(NN, 2), 64, 0, stream>>>(X, l0w1, l0b1, l0w2, l0b2, HS);
    for (int li = 0; li < 5; li++) {
        const float* hp = (li == 0) ? HS : H;
        int hGs = (li == 0) ? GHS : GH;
        k_gin<<<dim3(NN, 2), 64, 0, stream>>>(C, hp, hGs, gw1, gb1, gw2, gb2,
                                              geps, li, HS + (li + 1) * GH, GHS);
        k_bn<<<2, 256, 0, stream>>>(HS + (li + 1) * GH, GHS, H, GH,
                                    gga + li * F, gbe + li * F);
    }
    k_cvt2<<<(6 * NN * F + 255) / 256, 256, 0, stream>>>(HS, hbhi, hblo);
    k_gedT2<<<6 * KD, 64, 0, stream>>>(ged, gThi, gTlo);
    k_wprep3<<<1, 256, 0, stream>>>(wih, whh, waw, vw, bih, bhh, wab, vat, vb, wpack);
    k_t1m2<<<dim3(16, 3, 6), 256, 0, stream>>>(gThi, gTlo, hbhi, hblo, T1f);
    k_mega6<<<dim3(2, NN), 192, 0, stream>>>(T1f, HS + GHS, wpack,
                                             q1w, q1b, q2w, q2b, kw, kb, out);
}